// Round 5
// baseline (607.488 us; speedup 1.0000x reference)
//
#include <hip/hip_runtime.h>
#include <hip/hip_bf16.h>

#define NB 4
#define NC 512
#define ND 64
#define HW 4096
#define SPIN 6400

typedef _Float16 f16;
typedef _Float16 f16x8 __attribute__((ext_vector_type(8)));
typedef short s16x8 __attribute__((ext_vector_type(8)));
typedef float f32x4 __attribute__((ext_vector_type(4)));
typedef unsigned short ushortT;

__device__ __forceinline__ unsigned short f32_to_bf16(float x) {
  union { float f; unsigned u; } v; v.f = x;
  unsigned r = v.u + 0x7FFFu + ((v.u >> 16) & 1u);
  return (unsigned short)(r >> 16);
}

__device__ __forceinline__ void stv(float* p, float v) { *p = v; }
__device__ __forceinline__ void stv(f16* p, float v) { *p = (f16)v; }
__device__ __forceinline__ void stv(unsigned short* p, float v) { *p = f32_to_bf16(v); }

// pack two f32 -> bf16x2 in one u32 (compiler emits v_cvt_pk_bf16_f32)
__device__ __forceinline__ unsigned pk_bf16(float a, float b) {
  __hip_bfloat162 h = __float22bfloat162_rn(float2{a, b});
  union { __hip_bfloat162 h2; unsigned u; } c; c.h2 = h;
  return c.u;
}

// ---------------- all weights f32 -> f16, one launch ----------------
__global__ __launch_bounds__(256) void cvtw_kernel(const float* __restrict__ fw,
                                                   const float* __restrict__ gw,
                                                   const float* __restrict__ hw,
                                                   const float* __restrict__ ow,
                                                   f16* __restrict__ dst) {
  int i = blockIdx.x * 256 + threadIdx.x;
  const float* src; int off;
  if (i < 32768) { src = fw; off = 0; }
  else if (i < 65536) { src = gw; off = 32768; }
  else if (i < 327680) { src = hw; off = 65536; }
  else { src = ow; off = 327680; }
  dst[i] = (f16)src[i - off];
}

// ---------------- transpose+cvt: f32 [b][512][4096] -> f16 [b][4096][512] ----------------
__global__ __launch_bounds__(256) void tcvt_kernel(const float* __restrict__ in,
                                                   f16* __restrict__ out) {
  __shared__ float Xs[64][65];
  int p0 = blockIdx.x * 64, c0 = blockIdx.y * 64, b = blockIdx.z;
  int t = threadIdx.x;
  const float* ib = in + ((size_t)b * NC + c0) * HW + p0;
  int pl = t & 63, cg = t >> 6;
#pragma unroll
  for (int k = 0; k < 16; ++k) {
    int c = cg * 16 + k;
    Xs[c][pl] = ib[(size_t)c * HW + pl];
  }
  __syncthreads();
  int p = t >> 2, cb = (t & 3) * 16;
  union { f16 h[16]; float4 q[2]; } u;
#pragma unroll
  for (int j = 0; j < 16; ++j) u.h[j] = (f16)Xs[cb + j][p];
  f16* ob = out + ((size_t)b * HW + p0 + p) * NC + c0 + cb;
  *(float4*)(ob) = u.q[0];
  *(float4*)(ob + 8) = u.q[1];
}

// ---------------- fused bilinear-resize(80->64) + transpose + cvt for style ----------------
__global__ __launch_bounds__(256) void rstcvt_kernel(const float* __restrict__ X,
                                                     f16* __restrict__ Y) {
  __shared__ float Xs[64 * 165];
  int oy = blockIdx.x, c0 = blockIdx.y * 64, b = blockIdx.z;
  float syf = fmaxf((oy + 0.5f) * 1.25f - 0.5f, 0.f);
  int y0 = (int)syf; int y1 = min(y0 + 1, 79); float wy = syf - (float)y0;
  int t = threadIdx.x;
  const float* Xb = X + ((size_t)b * NC + c0) * SPIN;
#pragma unroll
  for (int k = 0; k < 10; ++k) {
    int idx = t + k * 256;
    int c = idx / 40;
    int rem = idx - c * 40;
    int yy = rem / 20;
    int x4 = rem - yy * 20;
    int ysrc = yy ? y1 : y0;
    float4 v = *(const float4*)(Xb + (size_t)c * SPIN + ysrc * 80 + x4 * 4);
    float* d = Xs + c * 165 + yy * 82 + x4 * 4;
    d[0] = v.x; d[1] = v.y; d[2] = v.z; d[3] = v.w;
  }
  __syncthreads();
  int ox = t >> 2, cb = (t & 3) * 16;
  float sxf = fmaxf((ox + 0.5f) * 1.25f - 0.5f, 0.f);
  int x0 = (int)sxf; int x1 = min(x0 + 1, 79); float wx = sxf - (float)x0;
  union { f16 h[16]; float4 q[2]; } u;
#pragma unroll
  for (int j = 0; j < 16; ++j) {
    const float* base = Xs + (cb + j) * 165;
    float a0 = base[x0], a1 = base[x1];
    float b0 = base[82 + x0], b1 = base[82 + x1];
    float r0 = a0 + (a1 - a0) * wx;
    float r1 = b0 + (b1 - b0) * wx;
    u.h[j] = (f16)(r0 + (r1 - r0) * wy);
  }
  f16* ob = Y + ((size_t)b * HW + oy * 64 + ox) * NC + c0 + cb;
  *(float4*)(ob) = u.q[0];
  *(float4*)(ob + 8) = u.q[1];
}

// ---------------- f & g conv1x1 fused, position-major out (O=64) ----------------
__global__ __launch_bounds__(256) void convpm2_kernel(const f16* __restrict__ X0,
                                                      const f16* __restrict__ X1,
                                                      const f16* __restrict__ W01,
                                                      const float* __restrict__ b0,
                                                      const float* __restrict__ b1,
                                                      f16* __restrict__ Y0,
                                                      f16* __restrict__ Y1) {
  int sel = blockIdx.z >> 2;
  int b = blockIdx.z & 3;
  const f16* X = sel ? X1 : X0;
  const f16* W = W01 + sel * (ND * NC);
  const float* bias = sel ? b1 : b0;
  f16* Y = sel ? Y1 : Y0;
  int t = threadIdx.x, l = t & 63, w = t >> 6;
  int pw = blockIdx.x * 256 + w * 64;
  int l4 = l & 15, g = l >> 4;
  f32x4 acc[4][4] = {};
  const f16* Xb = X + ((size_t)b * HW + pw) * NC;
  for (int kk = 0; kk < 16; ++kk) {
    int co = kk * 32 + g * 8;
    f16x8 a[4], bb[4];
#pragma unroll
    for (int ms = 0; ms < 4; ++ms) a[ms] = *(const f16x8*)(Xb + (size_t)(ms * 16 + l4) * NC + co);
#pragma unroll
    for (int ct = 0; ct < 4; ++ct) bb[ct] = *(const f16x8*)(W + (size_t)(ct * 16 + l4) * NC + co);
#pragma unroll
    for (int ms = 0; ms < 4; ++ms)
#pragma unroll
      for (int ct = 0; ct < 4; ++ct)
        acc[ms][ct] = __builtin_amdgcn_mfma_f32_16x16x32_f16(a[ms], bb[ct], acc[ms][ct], 0, 0, 0);
  }
  float bv[4];
#pragma unroll
  for (int ct = 0; ct < 4; ++ct) bv[ct] = bias[ct * 16 + l4];
  f16* Yb = Y + ((size_t)b * HW + pw) * ND;
#pragma unroll
  for (int ms = 0; ms < 4; ++ms)
#pragma unroll
    for (int ct = 0; ct < 4; ++ct)
#pragma unroll
      for (int r = 0; r < 4; ++r)
        Yb[(size_t)(ms * 16 + g * 4 + r) * ND + ct * 16 + l4] = (f16)(acc[ms][ct][r] + bv[ct]);
}

// ---------------- conv1x1, channel-major out ----------------
template <typename OUT_T>
__global__ __launch_bounds__(256) void convcm_kernel(const f16* __restrict__ X,
                                                     const f16* __restrict__ W,
                                                     const float* __restrict__ bias,
                                                     OUT_T* __restrict__ Y, int O) {
  int b = blockIdx.z;
  int o0 = blockIdx.x * 64;
  int t = threadIdx.x, l = t & 63, w = t >> 6;
  int pw = blockIdx.y * 256 + w * 64;
  int l4 = l & 15, g = l >> 4;
  f32x4 acc[4][4] = {};
  const f16* Xb = X + ((size_t)b * HW + pw) * NC;
  const f16* Wb = W + (size_t)o0 * NC;
  for (int kk = 0; kk < 16; ++kk) {
    int co = kk * 32 + g * 8;
    f16x8 a[4], bb[4];
#pragma unroll
    for (int ms = 0; ms < 4; ++ms) a[ms] = *(const f16x8*)(Wb + (size_t)(ms * 16 + l4) * NC + co);
#pragma unroll
    for (int ct = 0; ct < 4; ++ct) bb[ct] = *(const f16x8*)(Xb + (size_t)(ct * 16 + l4) * NC + co);
#pragma unroll
    for (int ms = 0; ms < 4; ++ms)
#pragma unroll
      for (int ct = 0; ct < 4; ++ct)
        acc[ms][ct] = __builtin_amdgcn_mfma_f32_16x16x32_f16(a[ms], bb[ct], acc[ms][ct], 0, 0, 0);
  }
  float bv[4][4];
#pragma unroll
  for (int ms = 0; ms < 4; ++ms)
#pragma unroll
    for (int r = 0; r < 4; ++r) bv[ms][r] = bias[o0 + ms * 16 + g * 4 + r];
#pragma unroll
  for (int ms = 0; ms < 4; ++ms)
#pragma unroll
    for (int ct = 0; ct < 4; ++ct)
#pragma unroll
      for (int r = 0; r < 4; ++r) {
        float val = acc[ms][ct][r] + bv[ms][r];
        stv(&Y[((size_t)b * O + o0 + ms * 16 + g * 4 + r) * HW + pw + ct * 16 + l4], val);
      }
}

// ---------------- flash attention: wave-private P (swapped QK), 1 barrier/iter ----------------
// FT,GT: f16 [b][4096][64]; HC: bf16 [b][512][4096]; MIDT: f16 [b][4096][512]
// grid 512 x 512thr: block = m-tile 32 (2 m-frags) x all 512 ch (4 quarters); wave=(mf,cq)
__global__ __launch_bounds__(512, 4) void attn_kernel(const f16* __restrict__ FT,
                                                      const f16* __restrict__ GT,
                                                      const unsigned short* __restrict__ HC,
                                                      f16* __restrict__ MIDT) {
  __shared__ __align__(16) char LDS[65536];  // K dbuf 2x16KB @0, P 8x4KB @32768
  int bid = blockIdx.x;
  int b = (bid & 7) >> 1;                    // batch -> XCD pair
  int mt = ((bid >> 3) << 1) | (bid & 1);
  int m0 = mt * 32;
  int t = threadIdx.x, l = t & 63, w = t >> 6;
  int l4 = l & 15, hi = l >> 4;
  int mf = w >> 2;     // m-frag 0..1
  int cq = w & 3;      // channel quarter 0..3
  int mr = m0 + mf * 16;

  // Q as B-operand: B[col=m=l4][k=c=hi*8+j]
  const f16* Fb = FT + ((size_t)b * HW + mr + l4) * ND + hi * 8;
  f16x8 qa0 = *(const f16x8*)(Fb);
  f16x8 qa1 = *(const f16x8*)(Fb + 32);

  const f16* Gb = GT + (size_t)b * HW * ND;
  const unsigned short* Hb = HC + ((size_t)b * NC + cq * 128) * HW;

  char* Ps = LDS + 32768 + w * 4096;         // wave-private 16m x 128n bf16
  const int psw = (l4 & 7) << 4;

  f32x4 acc[8] = {};
  float den = 0.f;

  // K staging: 2 slots/thread (rows t>>3 and t>>3+64, chunk t&7)
  int row0 = t >> 3, chunk0 = t & 7;
  int ka0 = (row0 * 128 + chunk0 * 16) ^ ((row0 & 7) << 4);
  int ka1 = ka0 + 64 * 128;                  // (row0+64)&7 == row0&7
  const f16* gs0 = Gb + (size_t)row0 * ND + chunk0 * 8;
  const f16* gs1 = gs0 + (size_t)64 * ND;

  {  // prologue: tile 0 -> buf 0
    f16x8 a = *(const f16x8*)gs0;
    f16x8 c = *(const f16x8*)gs1;
    *(f16x8*)(LDS + ka0) = a;
    *(f16x8*)(LDS + ka1) = c;
  }
  __syncthreads();

  int cur = 0;
  for (int it = 0; it < 32; ++it) {
    int n0 = it * 128;
    // issue next K tile loads (hide under whole iteration)
    f16x8 kn0, kn1;
    if (it < 31) {
      kn0 = *(const f16x8*)(gs0 + (size_t)(n0 + 128) * ND);
      kn1 = *(const f16x8*)(gs1 + (size_t)(n0 + 128) * ND);
    }
    // ---- QK (swapped: A=K so lane's S-col = its m) + exp + wave-private P store ----
    const char* Kc = LDS + cur * 16384;
#pragma unroll
    for (int nf = 0; nf < 8; ++nf) {
      const char* kr = Kc + (nf * 16 + l4) * 128;
      f16x8 kb0 = *(const f16x8*)(kr + ((hi * 16) ^ psw));
      f16x8 kb1 = *(const f16x8*)(kr + (((4 + hi) * 16) ^ psw));
      f32x4 s = {};
      s = __builtin_amdgcn_mfma_f32_16x16x32_f16(kb0, qa0, s, 0, 0, 0);
      s = __builtin_amdgcn_mfma_f32_16x16x32_f16(kb1, qa1, s, 0, 0, 0);
      float p0 = __expf(s[0]), p1 = __expf(s[1]), p2 = __expf(s[2]), p3 = __expf(s[3]);
      den += (p0 + p1) + (p2 + p3);
      unsigned long long q = (unsigned long long)pk_bf16(p0, p1) |
                             ((unsigned long long)pk_bf16(p2, p3) << 32);
      *(unsigned long long*)(Ps + ((l4 * 256 + nf * 32 + hi * 8) ^ psw)) = q;
    }
    asm volatile("s_waitcnt lgkmcnt(0)" ::: "memory");  // P writes visible to own reads
    // ---- PV A-frags from wave-private P ----
    s16x8 pa[4];
#pragma unroll
    for (int kc = 0; kc < 4; ++kc)
      pa[kc] = *(const s16x8*)(Ps + ((l4 * 256 + kc * 64 + hi * 16) ^ psw));
    // ---- PV: 8 c-frags x 4 k-chunks, V pipelined one c-frag ahead ----
    const unsigned short* hp = Hb + (size_t)l4 * HW + n0 + hi * 8;
    s16x8 vb[4];
#pragma unroll
    for (int kc = 0; kc < 4; ++kc) vb[kc] = *(const s16x8*)(hp + kc * 32);
#pragma unroll
    for (int cf = 0; cf < 8; ++cf) {
      s16x8 vn[4];
      if (cf < 7) {
        const unsigned short* hq = hp + (size_t)(cf + 1) * 16 * HW;
#pragma unroll
        for (int kc = 0; kc < 4; ++kc) vn[kc] = *(const s16x8*)(hq + kc * 32);
      }
      __builtin_amdgcn_s_setprio(1);
#pragma unroll
      for (int kc = 0; kc < 4; ++kc)
        acc[cf] = __builtin_amdgcn_mfma_f32_16x16x32_bf16(pa[kc], vb[kc], acc[cf], 0, 0, 0);
      __builtin_amdgcn_s_setprio(0);
#pragma unroll
      for (int kc = 0; kc < 4; ++kc) vb[kc] = vn[kc];
    }
    // ---- stage next K tile, single barrier ----
    if (it < 31) {
      char* Kn = LDS + (cur ^ 1) * 16384;
      *(f16x8*)(Kn + ka0) = kn0;
      *(f16x8*)(Kn + ka1) = kn1;
    }
    __syncthreads();
    cur ^= 1;
  }

  // den: reduce over lanes sharing l4 (l^16, l^32)
  den += __shfl_xor(den, 16);
  den += __shfl_xor(den, 32);
  float rd = 1.f / den;
  float rdv[4];
#pragma unroll
  for (int r = 0; r < 4; ++r) rdv[r] = __shfl(rd, hi * 4 + r);
  // D layout: row(m) = hi*4+r, col(c) = l4
  f16* Mb = MIDT + ((size_t)b * HW + mr) * NC + cq * 128;
#pragma unroll
  for (int cf = 0; cf < 8; ++cf)
#pragma unroll
    for (int r = 0; r < 4; ++r)
      Mb[(size_t)(hi * 4 + r) * NC + cf * 16 + l4] = (f16)(acc[cf][r] * rdv[r]);
}

extern "C" void kernel_launch(void* const* d_in, const int* in_sizes, int n_in,
                              void* d_out, int out_size, void* d_ws, size_t ws_size,
                              hipStream_t stream) {
  const float* content = (const float*)d_in[0];
  const float* style   = (const float*)d_in[1];
  const float* f_w = (const float*)d_in[2];
  const float* f_b = (const float*)d_in[3];
  const float* g_w = (const float*)d_in[4];
  const float* g_b = (const float*)d_in[5];
  const float* h_w = (const float*)d_in[6];
  const float* h_b = (const float*)d_in[7];
  const float* out_w = (const float*)d_in[8];
  const float* out_b = (const float*)d_in[9];
  float* out = (float*)d_out;

  const size_t MB = 1ull << 20;
  char* base = (char*)d_ws;
  f16* contentT = (f16*)base;            // [0,16M) dead after f-conv
  f16* midT     = (f16*)base;            // reuse
  unsigned short* hC = (unsigned short*)(base + 16 * MB);  // [16,32M)
  f16* fT = (f16*)(base + 32 * MB);
  f16* gT = (f16*)(base + 34 * MB);
  f16* styrT = (f16*)(base + 48 * MB);   // [48,64M)
  f16* w16 = (f16*)(base + 64 * MB);
  f16* fw16 = w16;
  f16* gw16 = w16 + 32768;
  f16* hw16 = w16 + 65536;
  f16* ow16 = w16 + 327680;

  cvtw_kernel<<<dim3(589824 / 256), 256, 0, stream>>>(f_w, g_w, h_w, out_w, w16);
  tcvt_kernel<<<dim3(HW / 64, NC / 64, NB), 256, 0, stream>>>(content, contentT);
  rstcvt_kernel<<<dim3(64, NC / 64, NB), 256, 0, stream>>>(style, styrT);
  convpm2_kernel<<<dim3(HW / 256, 1, 2 * NB), 256, 0, stream>>>(contentT, styrT, fw16, f_b, g_b, fT, gT);
  convcm_kernel<unsigned short><<<dim3(NC / 64, HW / 256, NB), 256, 0, stream>>>(styrT, hw16, h_b, hC, NC);
  attn_kernel<<<dim3(512), 512, 0, stream>>>(fT, gT, hC, midT);
  convcm_kernel<float><<<dim3(NC / 64, HW / 256, NB), 256, 0, stream>>>(midT, ow16, out_b, out, NC);
}

// Round 7
// 602.740 us; speedup vs baseline: 1.0079x; 1.0079x over previous
//
#include <hip/hip_runtime.h>

#define NB 4
#define NC 512
#define ND 64
#define HW 4096
#define SPIN 6400

typedef _Float16 f16;
typedef _Float16 f16x8 __attribute__((ext_vector_type(8)));
typedef short s16x8 __attribute__((ext_vector_type(8)));
typedef short s16x4 __attribute__((ext_vector_type(4)));
typedef float f32x4 __attribute__((ext_vector_type(4)));
typedef float f32x16 __attribute__((ext_vector_type(16)));

__device__ __forceinline__ unsigned short f32_to_bf16(float x) {
  union { float f; unsigned u; } v; v.f = x;
  unsigned r = v.u + 0x7FFFu + ((v.u >> 16) & 1u);
  return (unsigned short)(r >> 16);
}

__device__ __forceinline__ void stv(float* p, float v) { *p = v; }
__device__ __forceinline__ void stv(f16* p, float v) { *p = (f16)v; }
__device__ __forceinline__ void stv(unsigned short* p, float v) { *p = f32_to_bf16(v); }

__device__ __forceinline__ unsigned cvt_pk_bf16(float lo, float hi) {
  unsigned r;
  asm("v_cvt_pk_bf16_f32 %0, %1, %2" : "=v"(r) : "v"(lo), "v"(hi));
  return r;
}

// ---------------- all weights f32 -> f16, one launch ----------------
__global__ __launch_bounds__(256) void cvtw_kernel(const float* __restrict__ fw,
                                                   const float* __restrict__ gw,
                                                   const float* __restrict__ hw,
                                                   const float* __restrict__ ow,
                                                   f16* __restrict__ dst) {
  int i = blockIdx.x * 256 + threadIdx.x;
  const float* src; int off;
  if (i < 32768) { src = fw; off = 0; }
  else if (i < 65536) { src = gw; off = 32768; }
  else if (i < 327680) { src = hw; off = 65536; }
  else { src = ow; off = 327680; }
  dst[i] = (f16)src[i - off];
}

// ---------------- transpose+cvt: f32 [b][512][4096] -> f16 [b][4096][512] ----------------
__global__ __launch_bounds__(256) void tcvt_kernel(const float* __restrict__ in,
                                                   f16* __restrict__ out) {
  __shared__ float Xs[64][65];
  int p0 = blockIdx.x * 64, c0 = blockIdx.y * 64, b = blockIdx.z;
  int t = threadIdx.x;
  const float* ib = in + ((size_t)b * NC + c0) * HW + p0;
  int pl = t & 63, cg = t >> 6;
#pragma unroll
  for (int k = 0; k < 16; ++k) {
    int c = cg * 16 + k;
    Xs[c][pl] = ib[(size_t)c * HW + pl];
  }
  __syncthreads();
  int p = t >> 2, cb = (t & 3) * 16;
  union { f16 h[16]; float4 q[2]; } u;
#pragma unroll
  for (int j = 0; j < 16; ++j) u.h[j] = (f16)Xs[cb + j][p];
  f16* ob = out + ((size_t)b * HW + p0 + p) * NC + c0 + cb;
  *(float4*)(ob) = u.q[0];
  *(float4*)(ob + 8) = u.q[1];
}

// ---------------- fused bilinear-resize(80->64) + transpose + cvt for style ----------------
__global__ __launch_bounds__(256) void rstcvt_kernel(const float* __restrict__ X,
                                                     f16* __restrict__ Y) {
  __shared__ float Xs[64 * 165];
  int oy = blockIdx.x, c0 = blockIdx.y * 64, b = blockIdx.z;
  float syf = fmaxf((oy + 0.5f) * 1.25f - 0.5f, 0.f);
  int y0 = (int)syf; int y1 = min(y0 + 1, 79); float wy = syf - (float)y0;
  int t = threadIdx.x;
  const float* Xb = X + ((size_t)b * NC + c0) * SPIN;
#pragma unroll
  for (int k = 0; k < 10; ++k) {
    int idx = t + k * 256;
    int c = idx / 40;
    int rem = idx - c * 40;
    int yy = rem / 20;
    int x4 = rem - yy * 20;
    int ysrc = yy ? y1 : y0;
    float4 v = *(const float4*)(Xb + (size_t)c * SPIN + ysrc * 80 + x4 * 4);
    float* d = Xs + c * 165 + yy * 82 + x4 * 4;
    d[0] = v.x; d[1] = v.y; d[2] = v.z; d[3] = v.w;
  }
  __syncthreads();
  int ox = t >> 2, cb = (t & 3) * 16;
  float sxf = fmaxf((ox + 0.5f) * 1.25f - 0.5f, 0.f);
  int x0 = (int)sxf; int x1 = min(x0 + 1, 79); float wx = sxf - (float)x0;
  union { f16 h[16]; float4 q[2]; } u;
#pragma unroll
  for (int j = 0; j < 16; ++j) {
    const float* base = Xs + (cb + j) * 165;
    float a0 = base[x0], a1 = base[x1];
    float b0 = base[82 + x0], b1 = base[82 + x1];
    float r0 = a0 + (a1 - a0) * wx;
    float r1 = b0 + (b1 - b0) * wx;
    u.h[j] = (f16)(r0 + (r1 - r0) * wy);
  }
  f16* ob = Y + ((size_t)b * HW + oy * 64 + ox) * NC + c0 + cb;
  *(float4*)(ob) = u.q[0];
  *(float4*)(ob + 8) = u.q[1];
}

// ---------------- f & g conv1x1 fused, position-major out (O=64) ----------------
__global__ __launch_bounds__(256) void convpm2_kernel(const f16* __restrict__ X0,
                                                      const f16* __restrict__ X1,
                                                      const f16* __restrict__ W01,
                                                      const float* __restrict__ b0,
                                                      const float* __restrict__ b1,
                                                      f16* __restrict__ Y0,
                                                      f16* __restrict__ Y1) {
  int sel = blockIdx.z >> 2;
  int b = blockIdx.z & 3;
  const f16* X = sel ? X1 : X0;
  const f16* W = W01 + sel * (ND * NC);
  const float* bias = sel ? b1 : b0;
  f16* Y = sel ? Y1 : Y0;
  int t = threadIdx.x, l = t & 63, w = t >> 6;
  int pw = blockIdx.x * 256 + w * 64;
  int l4 = l & 15, g = l >> 4;
  f32x4 acc[4][4] = {};
  const f16* Xb = X + ((size_t)b * HW + pw) * NC;
  for (int kk = 0; kk < 16; ++kk) {
    int co = kk * 32 + g * 8;
    f16x8 a[4], bb[4];
#pragma unroll
    for (int ms = 0; ms < 4; ++ms) a[ms] = *(const f16x8*)(Xb + (size_t)(ms * 16 + l4) * NC + co);
#pragma unroll
    for (int ct = 0; ct < 4; ++ct) bb[ct] = *(const f16x8*)(W + (size_t)(ct * 16 + l4) * NC + co);
#pragma unroll
    for (int ms = 0; ms < 4; ++ms)
#pragma unroll
      for (int ct = 0; ct < 4; ++ct)
        acc[ms][ct] = __builtin_amdgcn_mfma_f32_16x16x32_f16(a[ms], bb[ct], acc[ms][ct], 0, 0, 0);
  }
  float bv[4];
#pragma unroll
  for (int ct = 0; ct < 4; ++ct) bv[ct] = bias[ct * 16 + l4];
  f16* Yb = Y + ((size_t)b * HW + pw) * ND;
#pragma unroll
  for (int ms = 0; ms < 4; ++ms)
#pragma unroll
    for (int ct = 0; ct < 4; ++ct)
#pragma unroll
      for (int r = 0; r < 4; ++r)
        Yb[(size_t)(ms * 16 + g * 4 + r) * ND + ct * 16 + l4] = (f16)(acc[ms][ct][r] + bv[ct]);
}

// ---------------- conv1x1, channel-major out ----------------
template <typename OUT_T>
__global__ __launch_bounds__(256) void convcm_kernel(const f16* __restrict__ X,
                                                     const f16* __restrict__ W,
                                                     const float* __restrict__ bias,
                                                     OUT_T* __restrict__ Y, int O) {
  int b = blockIdx.z;
  int o0 = blockIdx.x * 64;
  int t = threadIdx.x, l = t & 63, w = t >> 6;
  int pw = blockIdx.y * 256 + w * 64;
  int l4 = l & 15, g = l >> 4;
  f32x4 acc[4][4] = {};
  const f16* Xb = X + ((size_t)b * HW + pw) * NC;
  const f16* Wb = W + (size_t)o0 * NC;
  for (int kk = 0; kk < 16; ++kk) {
    int co = kk * 32 + g * 8;
    f16x8 a[4], bb[4];
#pragma unroll
    for (int ms = 0; ms < 4; ++ms) a[ms] = *(const f16x8*)(Wb + (size_t)(ms * 16 + l4) * NC + co);
#pragma unroll
    for (int ct = 0; ct < 4; ++ct) bb[ct] = *(const f16x8*)(Xb + (size_t)(ct * 16 + l4) * NC + co);
#pragma unroll
    for (int ms = 0; ms < 4; ++ms)
#pragma unroll
      for (int ct = 0; ct < 4; ++ct)
        acc[ms][ct] = __builtin_amdgcn_mfma_f32_16x16x32_f16(a[ms], bb[ct], acc[ms][ct], 0, 0, 0);
  }
  float bv[4][4];
#pragma unroll
  for (int ms = 0; ms < 4; ++ms)
#pragma unroll
    for (int r = 0; r < 4; ++r) bv[ms][r] = bias[o0 + ms * 16 + g * 4 + r];
#pragma unroll
  for (int ms = 0; ms < 4; ++ms)
#pragma unroll
    for (int ct = 0; ct < 4; ++ct)
#pragma unroll
      for (int r = 0; r < 4; ++r) {
        float val = acc[ms][ct][r] + bv[ms][r];
        stv(&Y[((size_t)b * O + o0 + ms * 16 + g * 4 + r) * HW + pw + ct * 16 + l4], val);
      }
}

// ---------------- flash attention v4: natural-slot in-register softmax ----------------
// FT,GT: f16 [b][4096][64]; HC: bf16 [b][512][4096]; MIDT: f16 [b][4096][512]
// grid 256: block = 128m x 256c; 8 waves = 4 m-frags x 2 c-quarters. Swapped QK
// (mfma32x32(K,Q)) puts lane's S-col = its m. P kept in NATURAL D slots (n_off =
// {0-3,8-11,16-19,24-27}+4hf); V loaded with the MATCHING interleaved n per slot
// (two 8B gathers per frag) -> slot-consistent PV, zero cross-lane P movement.
union PAu { unsigned u[4]; s16x8 v; };
union VBu { s16x4 h[2]; s16x8 v; };

__global__ __launch_bounds__(512, 2) void attn_kernel(const f16* __restrict__ FT,
                                                      const f16* __restrict__ GT,
                                                      const unsigned short* __restrict__ HC,
                                                      f16* __restrict__ MIDT) {
  __shared__ __align__(16) char Ks[2][16384];  // [chunk=kc*2+hf: 8][row: 128] x 16B
  int bid = blockIdx.x;
  int b = (bid & 7) >> 1;                      // batch -> XCD pair
  int cs = bid & 1;                            // channel half (256 ch)
  int m0 = (bid >> 3) * 128;                   // m-tile of 128
  int t = threadIdx.x, l = t & 63, w = t >> 6;
  int lm = l & 31, hf = l >> 5;
  int mf = w >> 1, cq = w & 1;                 // wave: m-frag 0..3, c-quarter 0..1
  int mr = m0 + mf * 32;

  // Q B-frags: B[k=c][col=m=lm], c = kc*16 + hf*8 + j
  const f16* Fq = FT + ((size_t)b * HW + mr + lm) * ND + hf * 8;
  f16x8 q[4];
#pragma unroll
  for (int kc = 0; kc < 4; ++kc) q[kc] = *(const f16x8*)(Fq + kc * 16);

  const f16* Gb = GT + (size_t)b * HW * ND;
  // V gather base: row c = cs*256 + cq*128 + cf*32 + lm; col offset starts at +4*hf
  const unsigned short* hbase = HC + ((size_t)b * NC + cs * 256 + cq * 128 + lm) * HW + 4 * hf;

  f32x16 acc[4] = {};
  float den = 0.f;

  // K staging: wave cc stages chunk cc (c = cc*8..+7), rows rw and rw+64
  int cc = t >> 6, rw = t & 63;
  int ka0 = cc * 2048 + rw * 16;
  int ka1 = ka0 + 1024;
  const f16* gs0 = Gb + (size_t)rw * ND + cc * 8;
  const f16* gs1 = gs0 + (size_t)64 * ND;

  *(f16x8*)(Ks[0] + ka0) = *(const f16x8*)gs0;
  *(f16x8*)(Ks[0] + ka1) = *(const f16x8*)gs1;
  __syncthreads();

// V frag loads, slot-matched to natural P layout: frag 2nf <- n {0..3,8..11}+4hf,
// frag 2nf+1 <- n {16..19,24..27}+4hf (relative to n0+nf*32)
#define LOADV(dst, cfi)                                                      \
  do {                                                                       \
    const unsigned short* hr_ = hbase + (size_t)(cfi) * 32 * HW + n0;        \
    _Pragma("unroll") for (int nf_ = 0; nf_ < 4; ++nf_) {                    \
      dst[2 * nf_].h[0] = *(const s16x4*)(hr_ + nf_ * 32);                   \
      dst[2 * nf_].h[1] = *(const s16x4*)(hr_ + nf_ * 32 + 8);               \
      dst[2 * nf_ + 1].h[0] = *(const s16x4*)(hr_ + nf_ * 32 + 16);          \
      dst[2 * nf_ + 1].h[1] = *(const s16x4*)(hr_ + nf_ * 32 + 24);          \
    }                                                                        \
  } while (0)

  int cur = 0;
  for (int it = 0; it < 32; ++it) {
    const int n0 = it * 128;
    // next K tile global loads: in flight across the whole body
    f16x8 kn0, kn1;
    if (it < 31) {
      kn0 = *(const f16x8*)(gs0 + (size_t)(n0 + 128) * ND);
      kn1 = *(const f16x8*)(gs1 + (size_t)(n0 + 128) * ND);
    }
    // V prefetch for cf=0,1: latency hides under QK
    VBu vbA[8], vbB[8];
    LOADV(vbA, 0);
    LOADV(vbB, 1);

    // ---- QK (swapped: S^T, lane col = m) + exp + natural-slot pack ----
    PAu pa[8];
    const char* Kc = Ks[cur];
#pragma unroll
    for (int nf = 0; nf < 4; ++nf) {
      f32x16 s = {};
#pragma unroll
      for (int kc = 0; kc < 4; ++kc) {
        f16x8 kb = *(const f16x8*)(Kc + (kc * 2 + hf) * 2048 + (nf * 32 + lm) * 16);
        s = __builtin_amdgcn_mfma_f32_32x32x16_f16(kb, q[kc], s, 0, 0, 0);
      }
      float p[16];
#pragma unroll
      for (int r = 0; r < 16; ++r) { p[r] = __expf(s[r]); den += p[r]; }
      // natural slots: element e of frag 2nf  -> n_off = (e<4 ? e : e+4) + 4hf
      //                element e of frag 2nf+1 -> n_off = 16 + (e<4 ? e : e+4) + 4hf
      pa[2 * nf].u[0] = cvt_pk_bf16(p[0], p[1]);
      pa[2 * nf].u[1] = cvt_pk_bf16(p[2], p[3]);
      pa[2 * nf].u[2] = cvt_pk_bf16(p[4], p[5]);
      pa[2 * nf].u[3] = cvt_pk_bf16(p[6], p[7]);
      pa[2 * nf + 1].u[0] = cvt_pk_bf16(p[8], p[9]);
      pa[2 * nf + 1].u[1] = cvt_pk_bf16(p[10], p[11]);
      pa[2 * nf + 1].u[2] = cvt_pk_bf16(p[12], p[13]);
      pa[2 * nf + 1].u[3] = cvt_pk_bf16(p[14], p[15]);
    }
    // ---- PV: 4 c-frags x 8 k-chunks, V double-buffered 2 frags ahead ----
    __builtin_amdgcn_s_setprio(1);
#pragma unroll
    for (int kc = 0; kc < 8; ++kc)
      acc[0] = __builtin_amdgcn_mfma_f32_32x32x16_bf16(pa[kc].v, vbA[kc].v, acc[0], 0, 0, 0);
    __builtin_amdgcn_s_setprio(0);
    LOADV(vbA, 2);
    __builtin_amdgcn_s_setprio(1);
#pragma unroll
    for (int kc = 0; kc < 8; ++kc)
      acc[1] = __builtin_amdgcn_mfma_f32_32x32x16_bf16(pa[kc].v, vbB[kc].v, acc[1], 0, 0, 0);
    __builtin_amdgcn_s_setprio(0);
    LOADV(vbB, 3);
    __builtin_amdgcn_s_setprio(1);
#pragma unroll
    for (int kc = 0; kc < 8; ++kc)
      acc[2] = __builtin_amdgcn_mfma_f32_32x32x16_bf16(pa[kc].v, vbA[kc].v, acc[2], 0, 0, 0);
#pragma unroll
    for (int kc = 0; kc < 8; ++kc)
      acc[3] = __builtin_amdgcn_mfma_f32_32x32x16_bf16(pa[kc].v, vbB[kc].v, acc[3], 0, 0, 0);
    __builtin_amdgcn_s_setprio(0);
    // ---- stage next K tile; single barrier per iteration ----
    if (it < 31) {
      *(f16x8*)(Ks[cur ^ 1] + ka0) = kn0;
      *(f16x8*)(Ks[cur ^ 1] + ka1) = kn1;
    }
    __syncthreads();
    cur ^= 1;
  }
#undef LOADV

  // den: lane (lm,hf) holds its half's sum for m=lm; xor32 completes it
  den += __shfl_xor(den, 32);
  float rd = 1.f / den;
  f16* Mb = MIDT + ((size_t)b * HW + mr) * NC + cs * 256 + cq * 128 + lm;
#pragma unroll
  for (int r = 0; r < 16; ++r) {
    int mrow = (r & 3) + 8 * (r >> 2) + 4 * hf;
    float rv = __shfl(rd, mrow);  // lane mrow (lm=mrow) holds den for m=mrow
#pragma unroll
    for (int cf = 0; cf < 4; ++cf)
      Mb[(size_t)mrow * NC + cf * 32] = (f16)(acc[cf][r] * rv);
  }
}

extern "C" void kernel_launch(void* const* d_in, const int* in_sizes, int n_in,
                              void* d_out, int out_size, void* d_ws, size_t ws_size,
                              hipStream_t stream) {
  const float* content = (const float*)d_in[0];
  const float* style   = (const float*)d_in[1];
  const float* f_w = (const float*)d_in[2];
  const float* f_b = (const float*)d_in[3];
  const float* g_w = (const float*)d_in[4];
  const float* g_b = (const float*)d_in[5];
  const float* h_w = (const float*)d_in[6];
  const float* h_b = (const float*)d_in[7];
  const float* out_w = (const float*)d_in[8];
  const float* out_b = (const float*)d_in[9];
  float* out = (float*)d_out;

  const size_t MB = 1ull << 20;
  char* base = (char*)d_ws;
  f16* contentT = (f16*)base;            // [0,16M) dead after f-conv
  f16* midT     = (f16*)base;            // reuse
  unsigned short* hC = (unsigned short*)(base + 16 * MB);  // [16,32M)
  f16* fT = (f16*)(base + 32 * MB);
  f16* gT = (f16*)(base + 34 * MB);
  f16* styrT = (f16*)(base + 48 * MB);   // [48,64M)
  f16* w16 = (f16*)(base + 64 * MB);
  f16* fw16 = w16;
  f16* gw16 = w16 + 32768;
  f16* hw16 = w16 + 65536;
  f16* ow16 = w16 + 327680;

  cvtw_kernel<<<dim3(589824 / 256), 256, 0, stream>>>(f_w, g_w, h_w, out_w, w16);
  tcvt_kernel<<<dim3(HW / 64, NC / 64, NB), 256, 0, stream>>>(content, contentT);
  rstcvt_kernel<<<dim3(64, NC / 64, NB), 256, 0, stream>>>(style, styrT);
  convpm2_kernel<<<dim3(HW / 256, 1, 2 * NB), 256, 0, stream>>>(contentT, styrT, fw16, f_b, g_b, fT, gT);
  convcm_kernel<unsigned short><<<dim3(NC / 64, HW / 256, NB), 256, 0, stream>>>(styrT, hw16, h_b, hC, NC);
  attn_kernel<<<dim3(256), 512, 0, stream>>>(fT, gT, hC, midT);
  convcm_kernel<float><<<dim3(NC / 64, HW / 256, NB), 256, 0, stream>>>(midT, ow16, out_b, out, NC);
}

// Round 8
// 466.733 us; speedup vs baseline: 1.3016x; 1.2914x over previous
//
#include <hip/hip_runtime.h>

#define NB 4
#define NC 512
#define ND 64
#define HW 4096
#define SPIN 6400

typedef _Float16 f16;
typedef _Float16 f16x8 __attribute__((ext_vector_type(8)));
typedef short s16x8 __attribute__((ext_vector_type(8)));
typedef float f32x4 __attribute__((ext_vector_type(4)));
typedef float f32x16 __attribute__((ext_vector_type(16)));
typedef unsigned short ushortT;

__device__ __forceinline__ unsigned short f32_to_bf16(float x) {
  union { float f; unsigned u; } v; v.f = x;
  unsigned r = v.u + 0x7FFFu + ((v.u >> 16) & 1u);
  return (unsigned short)(r >> 16);
}

__device__ __forceinline__ void stv(float* p, float v) { *p = v; }
__device__ __forceinline__ void stv(f16* p, float v) { *p = (f16)v; }
__device__ __forceinline__ void stv(unsigned short* p, float v) { *p = f32_to_bf16(v); }

__device__ __forceinline__ unsigned cvt_pk_bf16(float lo, float hi) {
  unsigned r;
  asm("v_cvt_pk_bf16_f32 %0, %1, %2" : "=v"(r) : "v"(lo), "v"(hi));
  return r;
}

// ---------------- all weights f32 -> f16, one launch ----------------
__global__ __launch_bounds__(256) void cvtw_kernel(const float* __restrict__ fw,
                                                   const float* __restrict__ gw,
                                                   const float* __restrict__ hw,
                                                   const float* __restrict__ ow,
                                                   f16* __restrict__ dst) {
  int i = blockIdx.x * 256 + threadIdx.x;
  const float* src; int off;
  if (i < 32768) { src = fw; off = 0; }
  else if (i < 65536) { src = gw; off = 32768; }
  else if (i < 327680) { src = hw; off = 65536; }
  else { src = ow; off = 327680; }
  dst[i] = (f16)src[i - off];
}

// ---------------- transpose+cvt: f32 [b][512][4096] -> f16 [b][4096][512] ----------------
__global__ __launch_bounds__(256) void tcvt_kernel(const float* __restrict__ in,
                                                   f16* __restrict__ out) {
  __shared__ float Xs[64][65];
  int p0 = blockIdx.x * 64, c0 = blockIdx.y * 64, b = blockIdx.z;
  int t = threadIdx.x;
  const float* ib = in + ((size_t)b * NC + c0) * HW + p0;
  int pl = t & 63, cg = t >> 6;
#pragma unroll
  for (int k = 0; k < 16; ++k) {
    int c = cg * 16 + k;
    Xs[c][pl] = ib[(size_t)c * HW + pl];
  }
  __syncthreads();
  int p = t >> 2, cb = (t & 3) * 16;
  union { f16 h[16]; float4 q[2]; } u;
#pragma unroll
  for (int j = 0; j < 16; ++j) u.h[j] = (f16)Xs[cb + j][p];
  f16* ob = out + ((size_t)b * HW + p0 + p) * NC + c0 + cb;
  *(float4*)(ob) = u.q[0];
  *(float4*)(ob + 8) = u.q[1];
}

// ---------------- fused bilinear-resize(80->64) + transpose + cvt for style ----------------
__global__ __launch_bounds__(256) void rstcvt_kernel(const float* __restrict__ X,
                                                     f16* __restrict__ Y) {
  __shared__ float Xs[64 * 165];
  int oy = blockIdx.x, c0 = blockIdx.y * 64, b = blockIdx.z;
  float syf = fmaxf((oy + 0.5f) * 1.25f - 0.5f, 0.f);
  int y0 = (int)syf; int y1 = min(y0 + 1, 79); float wy = syf - (float)y0;
  int t = threadIdx.x;
  const float* Xb = X + ((size_t)b * NC + c0) * SPIN;
#pragma unroll
  for (int k = 0; k < 10; ++k) {
    int idx = t + k * 256;
    int c = idx / 40;
    int rem = idx - c * 40;
    int yy = rem / 20;
    int x4 = rem - yy * 20;
    int ysrc = yy ? y1 : y0;
    float4 v = *(const float4*)(Xb + (size_t)c * SPIN + ysrc * 80 + x4 * 4);
    float* d = Xs + c * 165 + yy * 82 + x4 * 4;
    d[0] = v.x; d[1] = v.y; d[2] = v.z; d[3] = v.w;
  }
  __syncthreads();
  int ox = t >> 2, cb = (t & 3) * 16;
  float sxf = fmaxf((ox + 0.5f) * 1.25f - 0.5f, 0.f);
  int x0 = (int)sxf; int x1 = min(x0 + 1, 79); float wx = sxf - (float)x0;
  union { f16 h[16]; float4 q[2]; } u;
#pragma unroll
  for (int j = 0; j < 16; ++j) {
    const float* base = Xs + (cb + j) * 165;
    float a0 = base[x0], a1 = base[x1];
    float b0 = base[82 + x0], b1 = base[82 + x1];
    float r0 = a0 + (a1 - a0) * wx;
    float r1 = b0 + (b1 - b0) * wx;
    u.h[j] = (f16)(r0 + (r1 - r0) * wy);
  }
  f16* ob = Y + ((size_t)b * HW + oy * 64 + ox) * NC + c0 + cb;
  *(float4*)(ob) = u.q[0];
  *(float4*)(ob + 8) = u.q[1];
}

// ---------------- f & g conv1x1 fused, position-major out (O=64) ----------------
__global__ __launch_bounds__(256) void convpm2_kernel(const f16* __restrict__ X0,
                                                      const f16* __restrict__ X1,
                                                      const f16* __restrict__ W01,
                                                      const float* __restrict__ b0,
                                                      const float* __restrict__ b1,
                                                      f16* __restrict__ Y0,
                                                      f16* __restrict__ Y1) {
  int sel = blockIdx.z >> 2;
  int b = blockIdx.z & 3;
  const f16* X = sel ? X1 : X0;
  const f16* W = W01 + sel * (ND * NC);
  const float* bias = sel ? b1 : b0;
  f16* Y = sel ? Y1 : Y0;
  int t = threadIdx.x, l = t & 63, w = t >> 6;
  int pw = blockIdx.x * 256 + w * 64;
  int l4 = l & 15, g = l >> 4;
  f32x4 acc[4][4] = {};
  const f16* Xb = X + ((size_t)b * HW + pw) * NC;
  for (int kk = 0; kk < 16; ++kk) {
    int co = kk * 32 + g * 8;
    f16x8 a[4], bb[4];
#pragma unroll
    for (int ms = 0; ms < 4; ++ms) a[ms] = *(const f16x8*)(Xb + (size_t)(ms * 16 + l4) * NC + co);
#pragma unroll
    for (int ct = 0; ct < 4; ++ct) bb[ct] = *(const f16x8*)(W + (size_t)(ct * 16 + l4) * NC + co);
#pragma unroll
    for (int ms = 0; ms < 4; ++ms)
#pragma unroll
      for (int ct = 0; ct < 4; ++ct)
        acc[ms][ct] = __builtin_amdgcn_mfma_f32_16x16x32_f16(a[ms], bb[ct], acc[ms][ct], 0, 0, 0);
  }
  float bv[4];
#pragma unroll
  for (int ct = 0; ct < 4; ++ct) bv[ct] = bias[ct * 16 + l4];
  f16* Yb = Y + ((size_t)b * HW + pw) * ND;
#pragma unroll
  for (int ms = 0; ms < 4; ++ms)
#pragma unroll
    for (int ct = 0; ct < 4; ++ct)
#pragma unroll
      for (int r = 0; r < 4; ++r)
        Yb[(size_t)(ms * 16 + g * 4 + r) * ND + ct * 16 + l4] = (f16)(acc[ms][ct][r] + bv[ct]);
}

// ---------------- conv1x1, channel-major out; PERM applies sigma n-permutation ------
// sigma swaps col bits so attn's natural-slot V fragments are contiguous 16B loads:
// sigma(l4) = (l4&3) | ((l4&4)<<1) | ((l4&8)>>1)   (involution: 4-7 <-> 8-11)
template <typename OUT_T, bool PERM>
__global__ __launch_bounds__(256) void convcm_kernel(const f16* __restrict__ X,
                                                     const f16* __restrict__ W,
                                                     const float* __restrict__ bias,
                                                     OUT_T* __restrict__ Y, int O) {
  int b = blockIdx.z;
  int o0 = blockIdx.x * 64;
  int t = threadIdx.x, l = t & 63, w = t >> 6;
  int pw = blockIdx.y * 256 + w * 64;
  int l4 = l & 15, g = l >> 4;
  f32x4 acc[4][4] = {};
  const f16* Xb = X + ((size_t)b * HW + pw) * NC;
  const f16* Wb = W + (size_t)o0 * NC;
  for (int kk = 0; kk < 16; ++kk) {
    int co = kk * 32 + g * 8;
    f16x8 a[4], bb[4];
#pragma unroll
    for (int ms = 0; ms < 4; ++ms) a[ms] = *(const f16x8*)(Wb + (size_t)(ms * 16 + l4) * NC + co);
#pragma unroll
    for (int ct = 0; ct < 4; ++ct) bb[ct] = *(const f16x8*)(Xb + (size_t)(ct * 16 + l4) * NC + co);
#pragma unroll
    for (int ms = 0; ms < 4; ++ms)
#pragma unroll
      for (int ct = 0; ct < 4; ++ct)
        acc[ms][ct] = __builtin_amdgcn_mfma_f32_16x16x32_f16(a[ms], bb[ct], acc[ms][ct], 0, 0, 0);
  }
  int sl4 = PERM ? ((l4 & 3) | ((l4 & 4) << 1) | ((l4 & 8) >> 1)) : l4;
  float bv[4][4];
#pragma unroll
  for (int ms = 0; ms < 4; ++ms)
#pragma unroll
    for (int r = 0; r < 4; ++r) bv[ms][r] = bias[o0 + ms * 16 + g * 4 + r];
#pragma unroll
  for (int ms = 0; ms < 4; ++ms)
#pragma unroll
    for (int ct = 0; ct < 4; ++ct)
#pragma unroll
      for (int r = 0; r < 4; ++r) {
        float val = acc[ms][ct][r] + bv[ms][r];
        stv(&Y[((size_t)b * O + o0 + ms * 16 + g * 4 + r) * HW + pw + ct * 16 + sl4], val);
      }
}

// ---------------- flash attention v5: barrier-free, natural-slot in-register softmax ----
// FT,GT: f16 [b][4096][64]; HC: bf16 [b][512][4096] with sigma-permuted n within each
// 16-group; MIDT: f16 [b][4096][512].
// grid 512: block = 64m x 256c, 4 waves = 2mf x 2cq; wave = 32m x 128c.
// No LDS, no barriers: K and V read from L1/L2; K/V ping-pong prefetched 1 iter ahead.
union PAu { unsigned u[4]; s16x8 v; };

__global__ __launch_bounds__(256, 2) void attn_kernel(const f16* __restrict__ FT,
                                                      const f16* __restrict__ GT,
                                                      const unsigned short* __restrict__ HC,
                                                      f16* __restrict__ MIDT) {
  int bid = blockIdx.x;
  int b = (bid & 7) >> 1;                     // batch -> XCD pair
  int idx = ((bid >> 3) << 1) | (bid & 1);    // 0..127 within batch
  int mt = idx & 63;
  int cs = idx >> 6;
  int t = threadIdx.x, l = t & 63, w = t >> 6;
  int lm = l & 31, hf = l >> 5;
  int mf = w >> 1, cq = w & 1;
  int mr = mt * 64 + mf * 32;
  int cb = cs * 256 + cq * 128;

  // Q B-frags: B-row = m = mr+lm, slot (hf,j) -> c = kc*16 + hf*8 + j
  const f16* Fq = FT + ((size_t)b * HW + mr + lm) * ND + hf * 8;
  f16x8 q[4];
#pragma unroll
  for (int kc = 0; kc < 4; ++kc) q[kc] = *(const f16x8*)(Fq + kc * 16);

  // K A-frags: A-row = n = n0+lm, slot (hf,j) -> c = kc*16 + hf*8 + j
  const f16* kp = GT + (size_t)b * HW * ND + (size_t)lm * ND + hf * 8;
  // V B-frags: B-row = c = cb + cf*32 + lm; 16B at sigma-permuted position n0+kn*16+hf*8
  const unsigned short* vp = HC + ((size_t)b * NC + cb + lm) * HW + hf * 8;

  f32x16 acc[4] = {};
  float den = 0.f;

#define LOADK(kb, itx)                                                        \
  do {                                                                        \
    const f16* kq_ = kp + (size_t)(itx) * (32 * ND);                          \
    _Pragma("unroll") for (int kc_ = 0; kc_ < 4; ++kc_)                       \
        kb[kc_] = *(const f16x8*)(kq_ + kc_ * 16);                            \
  } while (0)

#define LOADV(vb, itx)                                                        \
  do {                                                                        \
    const unsigned short* vq_ = vp + (itx) * 32;                              \
    _Pragma("unroll") for (int cf_ = 0; cf_ < 4; ++cf_)                       \
        _Pragma("unroll") for (int kn_ = 0; kn_ < 2; ++kn_)                   \
        vb[cf_][kn_] = *(const s16x8*)(vq_ + (size_t)cf_ * 32 * HW + kn_ * 16); \
  } while (0)

#define BODY(kb, vb)                                                          \
  do {                                                                        \
    f32x16 s = {};                                                            \
    _Pragma("unroll") for (int kc_ = 0; kc_ < 4; ++kc_)                       \
        s = __builtin_amdgcn_mfma_f32_32x32x16_f16(kb[kc_], q[kc_], s, 0, 0, 0); \
    float p[16];                                                              \
    _Pragma("unroll") for (int r_ = 0; r_ < 16; ++r_) {                       \
      p[r_] = __expf(s[r_]);                                                  \
      den += p[r_];                                                           \
    }                                                                         \
    PAu pa[2];                                                                \
    pa[0].u[0] = cvt_pk_bf16(p[0], p[1]);                                     \
    pa[0].u[1] = cvt_pk_bf16(p[2], p[3]);                                     \
    pa[0].u[2] = cvt_pk_bf16(p[4], p[5]);                                     \
    pa[0].u[3] = cvt_pk_bf16(p[6], p[7]);                                     \
    pa[1].u[0] = cvt_pk_bf16(p[8], p[9]);                                     \
    pa[1].u[1] = cvt_pk_bf16(p[10], p[11]);                                   \
    pa[1].u[2] = cvt_pk_bf16(p[12], p[13]);                                   \
    pa[1].u[3] = cvt_pk_bf16(p[14], p[15]);                                   \
    __builtin_amdgcn_s_setprio(1);                                            \
    _Pragma("unroll") for (int cf_ = 0; cf_ < 4; ++cf_) {                     \
      acc[cf_] = __builtin_amdgcn_mfma_f32_32x32x16_bf16(pa[0].v, vb[cf_][0], acc[cf_], 0, 0, 0); \
      acc[cf_] = __builtin_amdgcn_mfma_f32_32x32x16_bf16(pa[1].v, vb[cf_][1], acc[cf_], 0, 0, 0); \
    }                                                                         \
    __builtin_amdgcn_s_setprio(0);                                            \
  } while (0)

  f16x8 kbA[4], kbB[4];
  s16x8 vbA[4][2], vbB[4][2];
  LOADK(kbA, 0);
  LOADV(vbA, 0);
  for (int it = 0; it < 128; it += 2) {
    LOADK(kbB, it + 1);
    LOADV(vbB, it + 1);
    BODY(kbA, vbA);
    LOADK(kbA, it + 2);  // it+2==128 reads unused (in-bounds of d_ws)
    LOADV(vbA, it + 2);
    BODY(kbB, vbB);
  }
#undef LOADK
#undef LOADV
#undef BODY

  // den: lane (lm,hf) holds its slot-half's sum for m=lm; xor32 completes it
  den += __shfl_xor(den, 32);
  float rd = 1.f / den;
  f16* Mb = MIDT + ((size_t)b * HW + mr) * NC + cb + lm;
#pragma unroll
  for (int r = 0; r < 16; ++r) {
    int mrow = (r & 3) + 8 * (r >> 2) + 4 * hf;
    float rv = __shfl(rd, mrow);  // lane mrow (lm=mrow) holds den for m=mrow
#pragma unroll
    for (int cf = 0; cf < 4; ++cf)
      Mb[(size_t)mrow * NC + cf * 32] = (f16)(acc[cf][r] * rv);
  }
}

extern "C" void kernel_launch(void* const* d_in, const int* in_sizes, int n_in,
                              void* d_out, int out_size, void* d_ws, size_t ws_size,
                              hipStream_t stream) {
  const float* content = (const float*)d_in[0];
  const float* style   = (const float*)d_in[1];
  const float* f_w = (const float*)d_in[2];
  const float* f_b = (const float*)d_in[3];
  const float* g_w = (const float*)d_in[4];
  const float* g_b = (const float*)d_in[5];
  const float* h_w = (const float*)d_in[6];
  const float* h_b = (const float*)d_in[7];
  const float* out_w = (const float*)d_in[8];
  const float* out_b = (const float*)d_in[9];
  float* out = (float*)d_out;

  const size_t MB = 1ull << 20;
  char* base = (char*)d_ws;
  f16* contentT = (f16*)base;            // [0,16M) dead after f-conv
  f16* midT     = (f16*)base;            // reuse
  unsigned short* hC = (unsigned short*)(base + 16 * MB);  // [16,32M)
  f16* fT = (f16*)(base + 32 * MB);
  f16* gT = (f16*)(base + 34 * MB);
  f16* styrT = (f16*)(base + 48 * MB);   // [48,64M)
  f16* w16 = (f16*)(base + 64 * MB);
  f16* fw16 = w16;
  f16* gw16 = w16 + 32768;
  f16* hw16 = w16 + 65536;
  f16* ow16 = w16 + 327680;

  cvtw_kernel<<<dim3(589824 / 256), 256, 0, stream>>>(f_w, g_w, h_w, out_w, w16);
  tcvt_kernel<<<dim3(HW / 64, NC / 64, NB), 256, 0, stream>>>(content, contentT);
  rstcvt_kernel<<<dim3(64, NC / 64, NB), 256, 0, stream>>>(style, styrT);
  convpm2_kernel<<<dim3(HW / 256, 1, 2 * NB), 256, 0, stream>>>(contentT, styrT, fw16, f_b, g_b, fT, gT);
  convcm_kernel<unsigned short, true><<<dim3(NC / 64, HW / 256, NB), 256, 0, stream>>>(styrT, hw16, h_b, hC, NC);
  attn_kernel<<<dim3(512), 256, 0, stream>>>(fT, gT, hC, midT);
  convcm_kernel<float, false><<<dim3(NC / 64, HW / 256, NB), 256, 0, stream>>>(midT, ow16, out_b, out, NC);
}

// Round 9
// 280.650 us; speedup vs baseline: 2.1646x; 1.6630x over previous
//
#include <hip/hip_runtime.h>

#define NB 4
#define NC 512
#define ND 64
#define HW 4096
#define SPIN 6400

typedef _Float16 f16;
typedef _Float16 f16x8 __attribute__((ext_vector_type(8)));
typedef short s16x8 __attribute__((ext_vector_type(8)));
typedef short s16x4 __attribute__((ext_vector_type(4)));
typedef float f32x4 __attribute__((ext_vector_type(4)));
typedef float f32x16 __attribute__((ext_vector_type(16)));
typedef unsigned short ushortT;

__device__ __forceinline__ unsigned short f32_to_bf16(float x) {
  union { float f; unsigned u; } v; v.f = x;
  unsigned r = v.u + 0x7FFFu + ((v.u >> 16) & 1u);
  return (unsigned short)(r >> 16);
}

__device__ __forceinline__ void stv(float* p, float v) { *p = v; }
__device__ __forceinline__ void stv(f16* p, float v) { *p = (f16)v; }
__device__ __forceinline__ void stv(unsigned short* p, float v) { *p = f32_to_bf16(v); }

__device__ __forceinline__ unsigned cvt_pk_bf16(float lo, float hi) {
  unsigned r;
  asm("v_cvt_pk_bf16_f32 %0, %1, %2" : "=v"(r) : "v"(lo), "v"(hi));
  return r;
}

// ---------------- all weights f32 -> f16, one launch ----------------
__global__ __launch_bounds__(256) void cvtw_kernel(const float* __restrict__ fw,
                                                   const float* __restrict__ gw,
                                                   const float* __restrict__ hw,
                                                   const float* __restrict__ ow,
                                                   f16* __restrict__ dst) {
  int i = blockIdx.x * 256 + threadIdx.x;
  const float* src; int off;
  if (i < 32768) { src = fw; off = 0; }
  else if (i < 65536) { src = gw; off = 32768; }
  else if (i < 327680) { src = hw; off = 65536; }
  else { src = ow; off = 327680; }
  dst[i] = (f16)src[i - off];
}

// ---------------- transpose+cvt: f32 [b][512][4096] -> f16 [b][4096][512] ----------------
__global__ __launch_bounds__(256) void tcvt_kernel(const float* __restrict__ in,
                                                   f16* __restrict__ out) {
  __shared__ float Xs[64][65];
  int p0 = blockIdx.x * 64, c0 = blockIdx.y * 64, b = blockIdx.z;
  int t = threadIdx.x;
  const float* ib = in + ((size_t)b * NC + c0) * HW + p0;
  int pl = t & 63, cg = t >> 6;
#pragma unroll
  for (int k = 0; k < 16; ++k) {
    int c = cg * 16 + k;
    Xs[c][pl] = ib[(size_t)c * HW + pl];
  }
  __syncthreads();
  int p = t >> 2, cb = (t & 3) * 16;
  union { f16 h[16]; float4 q[2]; } u;
#pragma unroll
  for (int j = 0; j < 16; ++j) u.h[j] = (f16)Xs[cb + j][p];
  f16* ob = out + ((size_t)b * HW + p0 + p) * NC + c0 + cb;
  *(float4*)(ob) = u.q[0];
  *(float4*)(ob + 8) = u.q[1];
}

// ---------------- fused bilinear-resize(80->64) + transpose + cvt for style ----------------
__global__ __launch_bounds__(256) void rstcvt_kernel(const float* __restrict__ X,
                                                     f16* __restrict__ Y) {
  __shared__ float Xs[64 * 165];
  int oy = blockIdx.x, c0 = blockIdx.y * 64, b = blockIdx.z;
  float syf = fmaxf((oy + 0.5f) * 1.25f - 0.5f, 0.f);
  int y0 = (int)syf; int y1 = min(y0 + 1, 79); float wy = syf - (float)y0;
  int t = threadIdx.x;
  const float* Xb = X + ((size_t)b * NC + c0) * SPIN;
#pragma unroll
  for (int k = 0; k < 10; ++k) {
    int idx = t + k * 256;
    int c = idx / 40;
    int rem = idx - c * 40;
    int yy = rem / 20;
    int x4 = rem - yy * 20;
    int ysrc = yy ? y1 : y0;
    float4 v = *(const float4*)(Xb + (size_t)c * SPIN + ysrc * 80 + x4 * 4);
    float* d = Xs + c * 165 + yy * 82 + x4 * 4;
    d[0] = v.x; d[1] = v.y; d[2] = v.z; d[3] = v.w;
  }
  __syncthreads();
  int ox = t >> 2, cb = (t & 3) * 16;
  float sxf = fmaxf((ox + 0.5f) * 1.25f - 0.5f, 0.f);
  int x0 = (int)sxf; int x1 = min(x0 + 1, 79); float wx = sxf - (float)x0;
  union { f16 h[16]; float4 q[2]; } u;
#pragma unroll
  for (int j = 0; j < 16; ++j) {
    const float* base = Xs + (cb + j) * 165;
    float a0 = base[x0], a1 = base[x1];
    float b0 = base[82 + x0], b1 = base[82 + x1];
    float r0 = a0 + (a1 - a0) * wx;
    float r1 = b0 + (b1 - b0) * wx;
    u.h[j] = (f16)(r0 + (r1 - r0) * wy);
  }
  f16* ob = Y + ((size_t)b * HW + oy * 64 + ox) * NC + c0 + cb;
  *(float4*)(ob) = u.q[0];
  *(float4*)(ob + 8) = u.q[1];
}

// ---------------- f & g conv1x1 fused, position-major out (O=64) ----------------
__global__ __launch_bounds__(256) void convpm2_kernel(const f16* __restrict__ X0,
                                                      const f16* __restrict__ X1,
                                                      const f16* __restrict__ W01,
                                                      const float* __restrict__ b0,
                                                      const float* __restrict__ b1,
                                                      f16* __restrict__ Y0,
                                                      f16* __restrict__ Y1) {
  int sel = blockIdx.z >> 2;
  int b = blockIdx.z & 3;
  const f16* X = sel ? X1 : X0;
  const f16* W = W01 + sel * (ND * NC);
  const float* bias = sel ? b1 : b0;
  f16* Y = sel ? Y1 : Y0;
  int t = threadIdx.x, l = t & 63, w = t >> 6;
  int pw = blockIdx.x * 256 + w * 64;
  int l4 = l & 15, g = l >> 4;
  f32x4 acc[4][4] = {};
  const f16* Xb = X + ((size_t)b * HW + pw) * NC;
  for (int kk = 0; kk < 16; ++kk) {
    int co = kk * 32 + g * 8;
    f16x8 a[4], bb[4];
#pragma unroll
    for (int ms = 0; ms < 4; ++ms) a[ms] = *(const f16x8*)(Xb + (size_t)(ms * 16 + l4) * NC + co);
#pragma unroll
    for (int ct = 0; ct < 4; ++ct) bb[ct] = *(const f16x8*)(W + (size_t)(ct * 16 + l4) * NC + co);
#pragma unroll
    for (int ms = 0; ms < 4; ++ms)
#pragma unroll
      for (int ct = 0; ct < 4; ++ct)
        acc[ms][ct] = __builtin_amdgcn_mfma_f32_16x16x32_f16(a[ms], bb[ct], acc[ms][ct], 0, 0, 0);
  }
  float bv[4];
#pragma unroll
  for (int ct = 0; ct < 4; ++ct) bv[ct] = bias[ct * 16 + l4];
  f16* Yb = Y + ((size_t)b * HW + pw) * ND;
#pragma unroll
  for (int ms = 0; ms < 4; ++ms)
#pragma unroll
    for (int ct = 0; ct < 4; ++ct)
#pragma unroll
      for (int r = 0; r < 4; ++r)
        Yb[(size_t)(ms * 16 + g * 4 + r) * ND + ct * 16 + l4] = (f16)(acc[ms][ct][r] + bv[ct]);
}

// ---------------- conv1x1, channel-major out ----------------
template <typename OUT_T>
__global__ __launch_bounds__(256) void convcm_kernel(const f16* __restrict__ X,
                                                     const f16* __restrict__ W,
                                                     const float* __restrict__ bias,
                                                     OUT_T* __restrict__ Y, int O) {
  int b = blockIdx.z;
  int o0 = blockIdx.x * 64;
  int t = threadIdx.x, l = t & 63, w = t >> 6;
  int pw = blockIdx.y * 256 + w * 64;
  int l4 = l & 15, g = l >> 4;
  f32x4 acc[4][4] = {};
  const f16* Xb = X + ((size_t)b * HW + pw) * NC;
  const f16* Wb = W + (size_t)o0 * NC;
  for (int kk = 0; kk < 16; ++kk) {
    int co = kk * 32 + g * 8;
    f16x8 a[4], bb[4];
#pragma unroll
    for (int ms = 0; ms < 4; ++ms) a[ms] = *(const f16x8*)(Wb + (size_t)(ms * 16 + l4) * NC + co);
#pragma unroll
    for (int ct = 0; ct < 4; ++ct) bb[ct] = *(const f16x8*)(Xb + (size_t)(ct * 16 + l4) * NC + co);
#pragma unroll
    for (int ms = 0; ms < 4; ++ms)
#pragma unroll
      for (int ct = 0; ct < 4; ++ct)
        acc[ms][ct] = __builtin_amdgcn_mfma_f32_16x16x32_f16(a[ms], bb[ct], acc[ms][ct], 0, 0, 0);
  }
  float bv[4][4];
#pragma unroll
  for (int ms = 0; ms < 4; ++ms)
#pragma unroll
    for (int r = 0; r < 4; ++r) bv[ms][r] = bias[o0 + ms * 16 + g * 4 + r];
#pragma unroll
  for (int ms = 0; ms < 4; ++ms)
#pragma unroll
    for (int ct = 0; ct < 4; ++ct)
#pragma unroll
      for (int r = 0; r < 4; ++r) {
        float val = acc[ms][ct][r] + bv[ms][r];
        stv(&Y[((size_t)b * O + o0 + ms * 16 + g * 4 + r) * HW + pw + ct * 16 + l4], val);
      }
}

// ---------------- flash attention v6: LDS-staged sigma-V, in-register softmax ----------
// FT,GT: f16 [b][4096][64]; HC: bf16 [b][512][4096]; MIDT: f16 [b][4096][512]
// grid 512 (2/CU): block = 64m x 256c (cs half), 4 waves = 2mf x 2cq; wave 32m x 128c.
// V staged global->LDS coalesced once per block-iter with sigma slot-permutation
// applied in the LDS write (pos q holds n = (q&3)+8*((q>>2)&1)+4*(q>>3) per 16-group),
// XOR-swizzled rows; PV B-frags = single ds_read_b128. K ping-pong from L1/L2.
union PAu { unsigned u[4]; s16x8 v; };
union VSu { s16x8 v; s16x4 h[2]; };

__global__ __launch_bounds__(256, 2) void attn_kernel(const f16* __restrict__ FT,
                                                      const f16* __restrict__ GT,
                                                      const unsigned short* __restrict__ HC,
                                                      f16* __restrict__ MIDT) {
  __shared__ __align__(16) char Vs[2][32768];  // [buf][c-local 256][128B]
  int bid = blockIdx.x;
  int b = (bid & 7) >> 1;   // batch -> XCD pair
  int cs = bid & 1;         // channel half
  int mt = bid >> 3;        // 0..63
  int t = threadIdx.x, l = t & 63, w = t >> 6;
  int lm = l & 31, hf = l >> 5;
  int mf = w >> 1, cq = w & 1;
  int mr = mt * 64 + mf * 32;
  int cqb = cq * 128;

  // Q B-frags: col = m = mr+lm, slot (hf,j) -> c = kc*16 + hf*8 + j
  const f16* Fq = FT + ((size_t)b * HW + mr + lm) * ND + hf * 8;
  f16x8 q[4];
#pragma unroll
  for (int kc = 0; kc < 4; ++kc) q[kc] = *(const f16x8*)(Fq + kc * 16);

  // K A-frags direct from global: row = n, slot (hf,j) -> c = kc*16+hf*8+j
  const f16* kp = GT + (size_t)b * HW * ND + (size_t)lm * ND + hf * 8;

  // V staging coords: thread stages rows cl = r*32+sc, 16B at n-seg nseg
  int sc = t >> 3;
  int nseg = (t & 7) * 8;
  int sb0 = ((nseg >> 4) * 32) + (((nseg >> 3) & 1) * 8);  // sigma'd byte offset
  const unsigned short* vsrc =
      HC + ((size_t)b * NC + cs * 256 + sc) * HW + nseg;

  f32x16 acc[4] = {};
  float den = 0.f;

#define STAGE_LOAD(n0x)                                                   \
  do {                                                                    \
    _Pragma("unroll") for (int r_ = 0; r_ < 8; ++r_)                      \
        vreg[r_].v = *(const s16x8*)(vsrc + (size_t)r_ * 32 * HW + (n0x)); \
  } while (0)

#define STAGE_WRITE(bufidx)                                               \
  do {                                                                    \
    _Pragma("unroll") for (int r_ = 0; r_ < 8; ++r_) {                    \
      int cl_ = r_ * 32 + sc;                                             \
      char* row_ = Vs[bufidx] + cl_ * 128;                                \
      int sw_ = (cl_ & 7) << 4;                                           \
      *(s16x4*)(row_ + (sb0 ^ sw_)) = vreg[r_].h[0];                      \
      *(s16x4*)(row_ + ((sb0 + 16) ^ sw_)) = vreg[r_].h[1];               \
    }                                                                     \
  } while (0)

#define PACK(sv, o)                                                       \
  do {                                                                    \
    float p_[16];                                                         \
    _Pragma("unroll") for (int r_ = 0; r_ < 16; ++r_) {                   \
      p_[r_] = __expf(sv[r_]);                                            \
      den += p_[r_];                                                      \
    }                                                                     \
    pa[o].u[0] = cvt_pk_bf16(p_[0], p_[1]);                               \
    pa[o].u[1] = cvt_pk_bf16(p_[2], p_[3]);                               \
    pa[o].u[2] = cvt_pk_bf16(p_[4], p_[5]);                               \
    pa[o].u[3] = cvt_pk_bf16(p_[6], p_[7]);                               \
    pa[o + 1].u[0] = cvt_pk_bf16(p_[8], p_[9]);                           \
    pa[o + 1].u[1] = cvt_pk_bf16(p_[10], p_[11]);                         \
    pa[o + 1].u[2] = cvt_pk_bf16(p_[12], p_[13]);                         \
    pa[o + 1].u[3] = cvt_pk_bf16(p_[14], p_[15]);                         \
  } while (0)

  // prologue: stage V tile 0, load K frags for n-block 0
  {
    VSu vreg[8];
    STAGE_LOAD(0);
    STAGE_WRITE(0);
  }
  __syncthreads();

  f16x8 kbA[4], kbB[4];
#pragma unroll
  for (int kc = 0; kc < 4; ++kc) kbA[kc] = *(const f16x8*)(kp + kc * 16);

  const int cl0 = cqb + lm;
  const int vsw = (lm & 7) << 4;

  int cur = 0;
  for (int it = 0; it < 64; ++it) {
    const int n0 = it * 64;
    // 1. issue V stage loads for next tile (hide under whole body)
    VSu vreg[8];
    if (it < 63) STAGE_LOAD(n0 + 64);
    // 2. K frags for second n-block of this iter
#pragma unroll
    for (int kc = 0; kc < 4; ++kc)
      kbB[kc] = *(const f16x8*)(kp + (size_t)(n0 + 32) * ND + kc * 16);
    // 3. S0 (n0..n0+31) + pack
    PAu pa[4];
    {
      f32x16 s = {};
#pragma unroll
      for (int kc = 0; kc < 4; ++kc)
        s = __builtin_amdgcn_mfma_f32_32x32x16_f16(kbA[kc], q[kc], s, 0, 0, 0);
      PACK(s, 0);
    }
    // 4. K frags for next iter's first n-block
    if (it < 63) {
#pragma unroll
      for (int kc = 0; kc < 4; ++kc)
        kbA[kc] = *(const f16x8*)(kp + (size_t)(n0 + 64) * ND + kc * 16);
    }
    // 5. S1 (+32) + pack
    {
      f32x16 s = {};
#pragma unroll
      for (int kc = 0; kc < 4; ++kc)
        s = __builtin_amdgcn_mfma_f32_32x32x16_f16(kbB[kc], q[kc], s, 0, 0, 0);
      PACK(s, 2);
    }
    // 6. PV from LDS: cf 0..3, vb double-buffered one cf ahead
    const char* Vc = Vs[cur];
    s16x8 vb[4], vn[4];
#pragma unroll
    for (int kn = 0; kn < 4; ++kn)
      vb[kn] = *(const s16x8*)(Vc + cl0 * 128 + ((kn * 32 + hf * 16) ^ vsw));
#pragma unroll
    for (int cf = 0; cf < 4; ++cf) {
      if (cf < 3) {
        const char* vr = Vc + (cl0 + (cf + 1) * 32) * 128;
#pragma unroll
        for (int kn = 0; kn < 4; ++kn)
          vn[kn] = *(const s16x8*)(vr + ((kn * 32 + hf * 16) ^ vsw));
      }
      __builtin_amdgcn_s_setprio(1);
#pragma unroll
      for (int kn = 0; kn < 4; ++kn)
        acc[cf] = __builtin_amdgcn_mfma_f32_32x32x16_bf16(pa[kn].v, vb[kn], acc[cf], 0, 0, 0);
      __builtin_amdgcn_s_setprio(0);
      if (cf < 3) {
#pragma unroll
        for (int kn = 0; kn < 4; ++kn) vb[kn] = vn[kn];
      }
    }
    // 7. write staged V -> other buffer (auto vmcnt wait on vreg use)
    if (it < 63) STAGE_WRITE(cur ^ 1);
    __syncthreads();
    cur ^= 1;
  }
#undef STAGE_LOAD
#undef STAGE_WRITE
#undef PACK

  // den: lane (lm,hf) holds its slot-half's sum for m = mr+lm
  den += __shfl_xor(den, 32);
  float rd = 1.f / den;
  f16* Mb = MIDT + ((size_t)b * HW + mr) * NC + cs * 256 + cqb + lm;
#pragma unroll
  for (int r = 0; r < 16; ++r) {
    int mrow = (r & 3) + 8 * (r >> 2) + 4 * hf;
    float rv = __shfl(rd, mrow);
#pragma unroll
    for (int cf = 0; cf < 4; ++cf)
      Mb[(size_t)mrow * NC + cf * 32] = (f16)(acc[cf][r] * rv);
  }
}

extern "C" void kernel_launch(void* const* d_in, const int* in_sizes, int n_in,
                              void* d_out, int out_size, void* d_ws, size_t ws_size,
                              hipStream_t stream) {
  const float* content = (const float*)d_in[0];
  const float* style   = (const float*)d_in[1];
  const float* f_w = (const float*)d_in[2];
  const float* f_b = (const float*)d_in[3];
  const float* g_w = (const float*)d_in[4];
  const float* g_b = (const float*)d_in[5];
  const float* h_w = (const float*)d_in[6];
  const float* h_b = (const float*)d_in[7];
  const float* out_w = (const float*)d_in[8];
  const float* out_b = (const float*)d_in[9];
  float* out = (float*)d_out;

  const size_t MB = 1ull << 20;
  char* base = (char*)d_ws;
  f16* contentT = (f16*)base;            // [0,16M) dead after f-conv
  f16* midT     = (f16*)base;            // reuse
  unsigned short* hC = (unsigned short*)(base + 16 * MB);  // [16,32M)
  f16* fT = (f16*)(base + 32 * MB);
  f16* gT = (f16*)(base + 34 * MB);
  f16* styrT = (f16*)(base + 48 * MB);   // [48,64M)
  f16* w16 = (f16*)(base + 64 * MB);
  f16* fw16 = w16;
  f16* gw16 = w16 + 32768;
  f16* hw16 = w16 + 65536;
  f16* ow16 = w16 + 327680;

  cvtw_kernel<<<dim3(589824 / 256), 256, 0, stream>>>(f_w, g_w, h_w, out_w, w16);
  tcvt_kernel<<<dim3(HW / 64, NC / 64, NB), 256, 0, stream>>>(content, contentT);
  rstcvt_kernel<<<dim3(64, NC / 64, NB), 256, 0, stream>>>(style, styrT);
  convpm2_kernel<<<dim3(HW / 256, 1, 2 * NB), 256, 0, stream>>>(contentT, styrT, fw16, f_b, g_b, fT, gT);
  convcm_kernel<unsigned short><<<dim3(NC / 64, HW / 256, NB), 256, 0, stream>>>(styrT, hw16, h_b, hC, NC);
  attn_kernel<<<dim3(512), 256, 0, stream>>>(fT, gT, hC, midT);
  convcm_kernel<float><<<dim3(NC / 64, HW / 256, NB), 256, 0, stream>>>(midT, ow16, out_b, out, NC);
}

// Round 10
// 276.442 us; speedup vs baseline: 2.1975x; 1.0152x over previous
//
#include <hip/hip_runtime.h>

#define NB 4
#define NC 512
#define ND 64
#define HW 4096
#define SPIN 6400

typedef _Float16 f16;
typedef _Float16 f16x8 __attribute__((ext_vector_type(8)));
typedef short s16x8 __attribute__((ext_vector_type(8)));
typedef short s16x4 __attribute__((ext_vector_type(4)));
typedef float f32x4 __attribute__((ext_vector_type(4)));
typedef float f32x16 __attribute__((ext_vector_type(16)));
typedef unsigned short ushortT;

__device__ __forceinline__ unsigned short f32_to_bf16(float x) {
  union { float f; unsigned u; } v; v.f = x;
  unsigned r = v.u + 0x7FFFu + ((v.u >> 16) & 1u);
  return (unsigned short)(r >> 16);
}

__device__ __forceinline__ void stv(float* p, float v) { *p = v; }
__device__ __forceinline__ void stv(f16* p, float v) { *p = (f16)v; }
__device__ __forceinline__ void stv(unsigned short* p, float v) { *p = f32_to_bf16(v); }

__device__ __forceinline__ unsigned cvt_pk_bf16(float lo, float hi) {
  unsigned r;
  asm("v_cvt_pk_bf16_f32 %0, %1, %2" : "=v"(r) : "v"(lo), "v"(hi));
  return r;
}

// ---------------- all weights f32 -> f16, one launch ----------------
__global__ __launch_bounds__(256) void cvtw_kernel(const float* __restrict__ fw,
                                                   const float* __restrict__ gw,
                                                   const float* __restrict__ hw,
                                                   const float* __restrict__ ow,
                                                   f16* __restrict__ dst) {
  int i = blockIdx.x * 256 + threadIdx.x;
  const float* src; int off;
  if (i < 32768) { src = fw; off = 0; }
  else if (i < 65536) { src = gw; off = 32768; }
  else if (i < 327680) { src = hw; off = 65536; }
  else { src = ow; off = 327680; }
  dst[i] = (f16)src[i - off];
}

// ---------------- transpose+cvt: f32 [b][512][4096] -> f16 [b][4096][512] ----------------
__global__ __launch_bounds__(256) void tcvt_kernel(const float* __restrict__ in,
                                                   f16* __restrict__ out) {
  __shared__ float Xs[64][65];
  int p0 = blockIdx.x * 64, c0 = blockIdx.y * 64, b = blockIdx.z;
  int t = threadIdx.x;
  const float* ib = in + ((size_t)b * NC + c0) * HW + p0;
  int pl = t & 63, cg = t >> 6;
#pragma unroll
  for (int k = 0; k < 16; ++k) {
    int c = cg * 16 + k;
    Xs[c][pl] = ib[(size_t)c * HW + pl];
  }
  __syncthreads();
  int p = t >> 2, cb = (t & 3) * 16;
  union { f16 h[16]; float4 q[2]; } u;
#pragma unroll
  for (int j = 0; j < 16; ++j) u.h[j] = (f16)Xs[cb + j][p];
  f16* ob = out + ((size_t)b * HW + p0 + p) * NC + c0 + cb;
  *(float4*)(ob) = u.q[0];
  *(float4*)(ob + 8) = u.q[1];
}

// ---------------- fused bilinear-resize(80->64) + transpose + cvt for style ----------------
__global__ __launch_bounds__(256) void rstcvt_kernel(const float* __restrict__ X,
                                                     f16* __restrict__ Y) {
  __shared__ float Xs[64 * 165];
  int oy = blockIdx.x, c0 = blockIdx.y * 64, b = blockIdx.z;
  float syf = fmaxf((oy + 0.5f) * 1.25f - 0.5f, 0.f);
  int y0 = (int)syf; int y1 = min(y0 + 1, 79); float wy = syf - (float)y0;
  int t = threadIdx.x;
  const float* Xb = X + ((size_t)b * NC + c0) * SPIN;
#pragma unroll
  for (int k = 0; k < 10; ++k) {
    int idx = t + k * 256;
    int c = idx / 40;
    int rem = idx - c * 40;
    int yy = rem / 20;
    int x4 = rem - yy * 20;
    int ysrc = yy ? y1 : y0;
    float4 v = *(const float4*)(Xb + (size_t)c * SPIN + ysrc * 80 + x4 * 4);
    float* d = Xs + c * 165 + yy * 82 + x4 * 4;
    d[0] = v.x; d[1] = v.y; d[2] = v.z; d[3] = v.w;
  }
  __syncthreads();
  int ox = t >> 2, cb = (t & 3) * 16;
  float sxf = fmaxf((ox + 0.5f) * 1.25f - 0.5f, 0.f);
  int x0 = (int)sxf; int x1 = min(x0 + 1, 79); float wx = sxf - (float)x0;
  union { f16 h[16]; float4 q[2]; } u;
#pragma unroll
  for (int j = 0; j < 16; ++j) {
    const float* base = Xs + (cb + j) * 165;
    float a0 = base[x0], a1 = base[x1];
    float b0 = base[82 + x0], b1 = base[82 + x1];
    float r0 = a0 + (a1 - a0) * wx;
    float r1 = b0 + (b1 - b0) * wx;
    u.h[j] = (f16)(r0 + (r1 - r0) * wy);
  }
  f16* ob = Y + ((size_t)b * HW + oy * 64 + ox) * NC + c0 + cb;
  *(float4*)(ob) = u.q[0];
  *(float4*)(ob + 8) = u.q[1];
}

// ---------------- f & g conv1x1 fused, position-major out (O=64) ----------------
__global__ __launch_bounds__(256) void convpm2_kernel(const f16* __restrict__ X0,
                                                      const f16* __restrict__ X1,
                                                      const f16* __restrict__ W01,
                                                      const float* __restrict__ b0,
                                                      const float* __restrict__ b1,
                                                      f16* __restrict__ Y0,
                                                      f16* __restrict__ Y1) {
  int sel = blockIdx.z >> 2;
  int b = blockIdx.z & 3;
  const f16* X = sel ? X1 : X0;
  const f16* W = W01 + sel * (ND * NC);
  const float* bias = sel ? b1 : b0;
  f16* Y = sel ? Y1 : Y0;
  int t = threadIdx.x, l = t & 63, w = t >> 6;
  int pw = blockIdx.x * 256 + w * 64;
  int l4 = l & 15, g = l >> 4;
  f32x4 acc[4][4] = {};
  const f16* Xb = X + ((size_t)b * HW + pw) * NC;
  for (int kk = 0; kk < 16; ++kk) {
    int co = kk * 32 + g * 8;
    f16x8 a[4], bb[4];
#pragma unroll
    for (int ms = 0; ms < 4; ++ms) a[ms] = *(const f16x8*)(Xb + (size_t)(ms * 16 + l4) * NC + co);
#pragma unroll
    for (int ct = 0; ct < 4; ++ct) bb[ct] = *(const f16x8*)(W + (size_t)(ct * 16 + l4) * NC + co);
#pragma unroll
    for (int ms = 0; ms < 4; ++ms)
#pragma unroll
      for (int ct = 0; ct < 4; ++ct)
        acc[ms][ct] = __builtin_amdgcn_mfma_f32_16x16x32_f16(a[ms], bb[ct], acc[ms][ct], 0, 0, 0);
  }
  float bv[4];
#pragma unroll
  for (int ct = 0; ct < 4; ++ct) bv[ct] = bias[ct * 16 + l4];
  f16* Yb = Y + ((size_t)b * HW + pw) * ND;
#pragma unroll
  for (int ms = 0; ms < 4; ++ms)
#pragma unroll
    for (int ct = 0; ct < 4; ++ct)
#pragma unroll
      for (int r = 0; r < 4; ++r)
        Yb[(size_t)(ms * 16 + g * 4 + r) * ND + ct * 16 + l4] = (f16)(acc[ms][ct][r] + bv[ct]);
}

// ---------------- conv1x1, channel-major out ----------------
template <typename OUT_T>
__global__ __launch_bounds__(256) void convcm_kernel(const f16* __restrict__ X,
                                                     const f16* __restrict__ W,
                                                     const float* __restrict__ bias,
                                                     OUT_T* __restrict__ Y, int O) {
  int b = blockIdx.z;
  int o0 = blockIdx.x * 64;
  int t = threadIdx.x, l = t & 63, w = t >> 6;
  int pw = blockIdx.y * 256 + w * 64;
  int l4 = l & 15, g = l >> 4;
  f32x4 acc[4][4] = {};
  const f16* Xb = X + ((size_t)b * HW + pw) * NC;
  const f16* Wb = W + (size_t)o0 * NC;
  for (int kk = 0; kk < 16; ++kk) {
    int co = kk * 32 + g * 8;
    f16x8 a[4], bb[4];
#pragma unroll
    for (int ms = 0; ms < 4; ++ms) a[ms] = *(const f16x8*)(Wb + (size_t)(ms * 16 + l4) * NC + co);
#pragma unroll
    for (int ct = 0; ct < 4; ++ct) bb[ct] = *(const f16x8*)(Xb + (size_t)(ct * 16 + l4) * NC + co);
#pragma unroll
    for (int ms = 0; ms < 4; ++ms)
#pragma unroll
      for (int ct = 0; ct < 4; ++ct)
        acc[ms][ct] = __builtin_amdgcn_mfma_f32_16x16x32_f16(a[ms], bb[ct], acc[ms][ct], 0, 0, 0);
  }
  float bv[4][4];
#pragma unroll
  for (int ms = 0; ms < 4; ++ms)
#pragma unroll
    for (int r = 0; r < 4; ++r) bv[ms][r] = bias[o0 + ms * 16 + g * 4 + r];
#pragma unroll
  for (int ms = 0; ms < 4; ++ms)
#pragma unroll
    for (int ct = 0; ct < 4; ++ct)
#pragma unroll
      for (int r = 0; r < 4; ++r) {
        float val = acc[ms][ct][r] + bv[ms][r];
        stv(&Y[((size_t)b * O + o0 + ms * 16 + g * 4 + r) * HW + pw + ct * 16 + l4], val);
      }
}

// ---------------- flash attention v7: cross-tile pipeline (PV lags QK by one n-tile) --
// FT,GT: f16 [b][4096][64]; HC: bf16 [b][512][4096]; MIDT: f16 [b][4096][512]
// grid 512 (2/CU): block = 64m x 256c, 4 waves = 2mf x 2cq; wave 32m x 128c.
// Per iter: [stage_load(it+1) | K(it+1) | QK(it) | PV(it-1) | exp/pack(it)] BARRIER
// [stage_write(it+1)].  Single mid-iter barrier; happens-before verified:
//   write(tile k)@iter k-1 post-bar(k-1); PV(tile k) reads @iter k+1 post-bar(k) -> safe
//   PV(tile k-1) reads @iter k pre-bar(k); write(tile k+1) same buf @iter k post-bar(k) -> safe
union PAu { unsigned u[4]; s16x8 v; };
union VSu { s16x8 v; s16x4 h[2]; };

__global__ __launch_bounds__(256, 2) void attn_kernel(const f16* __restrict__ FT,
                                                      const f16* __restrict__ GT,
                                                      const unsigned short* __restrict__ HC,
                                                      f16* __restrict__ MIDT) {
  __shared__ __align__(16) char Vs[2][32768];  // [buf][c-local 256][128B]
  int bid = blockIdx.x;
  int b = (bid & 7) >> 1;   // batch -> XCD pair
  int cs = bid & 1;         // channel half
  int mt = bid >> 3;        // 0..63
  int t = threadIdx.x, l = t & 63, w = t >> 6;
  int lm = l & 31, hf = l >> 5;
  int mf = w >> 1, cq = w & 1;
  int mr = mt * 64 + mf * 32;
  int cqb = cq * 128;

  // Q B-frags: col = m = mr+lm, slot (hf,j) -> c = kc*16 + hf*8 + j
  const f16* Fq = FT + ((size_t)b * HW + mr + lm) * ND + hf * 8;
  f16x8 q[4];
#pragma unroll
  for (int kc = 0; kc < 4; ++kc) q[kc] = *(const f16x8*)(Fq + kc * 16);

  // K A-frags direct from global: row = n, slot (hf,j) -> c = kc*16+hf*8+j
  const f16* kp = GT + (size_t)b * HW * ND + (size_t)lm * ND + hf * 8;

  // V staging coords: thread stages rows cl = r*32+sc, 16B at n-seg nseg
  int sc = t >> 3;
  int nseg = (t & 7) * 8;
  int sb0 = ((nseg >> 4) * 32) + (((nseg >> 3) & 1) * 8);  // sigma'd byte offset
  const unsigned short* vsrc =
      HC + ((size_t)b * NC + cs * 256 + sc) * HW + nseg;

  f32x16 acc[4] = {};
  float den = 0.f;

  const int cl0 = cqb + lm;
  const int vsw = (lm & 7) << 4;

#define STAGE_LOAD(n0x)                                                   \
  do {                                                                    \
    _Pragma("unroll") for (int r_ = 0; r_ < 8; ++r_)                      \
        vreg[r_].v = *(const s16x8*)(vsrc + (size_t)r_ * 32 * HW + (n0x)); \
  } while (0)

#define STAGE_WRITE(bufidx)                                               \
  do {                                                                    \
    _Pragma("unroll") for (int r_ = 0; r_ < 8; ++r_) {                    \
      int cl_ = r_ * 32 + sc;                                             \
      char* row_ = Vs[bufidx] + cl_ * 128;                                \
      int sw_ = (cl_ & 7) << 4;                                           \
      *(s16x4*)(row_ + (sb0 ^ sw_)) = vreg[r_].h[0];                      \
      *(s16x4*)(row_ + ((sb0 + 16) ^ sw_)) = vreg[r_].h[1];               \
    }                                                                     \
  } while (0)

#define PACK(sv, PA, o)                                                   \
  do {                                                                    \
    float p_[16];                                                         \
    _Pragma("unroll") for (int r_ = 0; r_ < 16; ++r_) {                   \
      p_[r_] = __expf(sv[r_]);                                            \
      den += p_[r_];                                                      \
    }                                                                     \
    PA[o].u[0] = cvt_pk_bf16(p_[0], p_[1]);                               \
    PA[o].u[1] = cvt_pk_bf16(p_[2], p_[3]);                               \
    PA[o].u[2] = cvt_pk_bf16(p_[4], p_[5]);                               \
    PA[o].u[3] = cvt_pk_bf16(p_[6], p_[7]);                               \
    PA[o + 1].u[0] = cvt_pk_bf16(p_[8], p_[9]);                           \
    PA[o + 1].u[1] = cvt_pk_bf16(p_[10], p_[11]);                         \
    PA[o + 1].u[2] = cvt_pk_bf16(p_[12], p_[13]);                         \
    PA[o + 1].u[3] = cvt_pk_bf16(p_[14], p_[15]);                         \
  } while (0)

#define PVBODY(PA, Vc)                                                    \
  do {                                                                    \
    s16x8 vb_[4], vn_[4];                                                 \
    _Pragma("unroll") for (int kn = 0; kn < 4; ++kn)                      \
        vb_[kn] = *(const s16x8*)((Vc) + cl0 * 128 + ((kn * 32 + hf * 16) ^ vsw)); \
    _Pragma("unroll") for (int cf = 0; cf < 4; ++cf) {                    \
      if (cf < 3) {                                                       \
        const char* vr_ = (Vc) + (cl0 + (cf + 1) * 32) * 128;             \
        _Pragma("unroll") for (int kn = 0; kn < 4; ++kn)                  \
            vn_[kn] = *(const s16x8*)(vr_ + ((kn * 32 + hf * 16) ^ vsw)); \
      }                                                                   \
      __builtin_amdgcn_s_setprio(1);                                      \
      _Pragma("unroll") for (int kn = 0; kn < 4; ++kn)                    \
          acc[cf] = __builtin_amdgcn_mfma_f32_32x32x16_bf16(PA[kn].v, vb_[kn], acc[cf], 0, 0, 0); \
      __builtin_amdgcn_s_setprio(0);                                      \
      if (cf < 3) {                                                       \
        _Pragma("unroll") for (int kn = 0; kn < 4; ++kn) vb_[kn] = vn_[kn]; \
      }                                                                   \
    }                                                                     \
  } while (0)

// One pipelined iteration: QK(IT) into PC; PV(IT-1) from PP (skipped if !DOPV);
// K for tile IT in KC; loads K(IT+1) into KN.
#define ITER(IT, PC, PP, KC, KN, DOPV)                                    \
  do {                                                                    \
    const int n0 = (IT) * 64;                                             \
    VSu vreg[8];                                                          \
    if ((IT) < 63) {                                                      \
      STAGE_LOAD(n0 + 64);                                                \
      _Pragma("unroll") for (int h_ = 0; h_ < 2; ++h_)                    \
          _Pragma("unroll") for (int kc = 0; kc < 4; ++kc)                \
          KN[h_][kc] = *(const f16x8*)(kp + (size_t)(n0 + 64 + h_ * 32) * ND + kc * 16); \
    }                                                                     \
    f32x16 s0 = {}, s1 = {};                                              \
    _Pragma("unroll") for (int kc = 0; kc < 4; ++kc)                      \
        s0 = __builtin_amdgcn_mfma_f32_32x32x16_f16(KC[0][kc], q[kc], s0, 0, 0, 0); \
    _Pragma("unroll") for (int kc = 0; kc < 4; ++kc)                      \
        s1 = __builtin_amdgcn_mfma_f32_32x32x16_f16(KC[1][kc], q[kc], s1, 0, 0, 0); \
    if (DOPV) {                                                           \
      const char* Vc_ = Vs[((IT) + 1) & 1]; /* == (IT-1)&1 */             \
      PVBODY(PP, Vc_);                                                    \
    }                                                                     \
    PACK(s0, PC, 0);                                                      \
    PACK(s1, PC, 2);                                                      \
    __syncthreads();                                                      \
    if ((IT) < 63) STAGE_WRITE(((IT) + 1) & 1);                           \
  } while (0)

  // prologue: stage V tile 0 -> buf0; K tile 0 -> kbP
  {
    VSu vreg[8];
    STAGE_LOAD(0);
    STAGE_WRITE(0);
  }
  f16x8 kbP[2][4], kbQ[2][4];
#pragma unroll
  for (int h = 0; h < 2; ++h)
#pragma unroll
    for (int kc = 0; kc < 4; ++kc)
      kbP[h][kc] = *(const f16x8*)(kp + (size_t)(h * 32) * ND + kc * 16);
  __syncthreads();

  PAu paA[4], paB[4];
  ITER(0, paA, paB, kbP, kbQ, false);
  for (int ito = 1; ito < 63; ito += 2) {
    ITER(ito, paB, paA, kbQ, kbP, true);
    ITER(ito + 1, paA, paB, kbP, kbQ, true);
  }
  ITER(63, paB, paA, kbQ, kbP, true);
  // epilogue: PV for tile 63 (in buf 1, pa = paB)
  PVBODY(paB, (const char*)Vs[1]);

#undef STAGE_LOAD
#undef STAGE_WRITE
#undef PACK
#undef PVBODY
#undef ITER

  // den: lane (lm,hf) holds its slot-half's sum for m = mr+lm
  den += __shfl_xor(den, 32);
  float rd = 1.f / den;
  f16* Mb = MIDT + ((size_t)b * HW + mr) * NC + cs * 256 + cqb + lm;
#pragma unroll
  for (int r = 0; r < 16; ++r) {
    int mrow = (r & 3) + 8 * (r >> 2) + 4 * hf;
    float rv = __shfl(rd, mrow);
#pragma unroll
    for (int cf = 0; cf < 4; ++cf)
      Mb[(size_t)mrow * NC + cf * 32] = (f16)(acc[cf][r] * rv);
  }
}

extern "C" void kernel_launch(void* const* d_in, const int* in_sizes, int n_in,
                              void* d_out, int out_size, void* d_ws, size_t ws_size,
                              hipStream_t stream) {
  const float* content = (const float*)d_in[0];
  const float* style   = (const float*)d_in[1];
  const float* f_w = (const float*)d_in[2];
  const float* f_b = (const float*)d_in[3];
  const float* g_w = (const float*)d_in[4];
  const float* g_b = (const float*)d_in[5];
  const float* h_w = (const float*)d_in[6];
  const float* h_b = (const float*)d_in[7];
  const float* out_w = (const float*)d_in[8];
  const float* out_b = (const float*)d_in[9];
  float* out = (float*)d_out;

  const size_t MB = 1ull << 20;
  char* base = (char*)d_ws;
  f16* contentT = (f16*)base;            // [0,16M) dead after f-conv
  f16* midT     = (f16*)base;            // reuse
  unsigned short* hC = (unsigned short*)(base + 16 * MB);  // [16,32M)
  f16* fT = (f16*)(base + 32 * MB);
  f16* gT = (f16*)(base + 34 * MB);
  f16* styrT = (f16*)(base + 48 * MB);   // [48,64M)
  f16* w16 = (f16*)(base + 64 * MB);
  f16* fw16 = w16;
  f16* gw16 = w16 + 32768;
  f16* hw16 = w16 + 65536;
  f16* ow16 = w16 + 327680;

  cvtw_kernel<<<dim3(589824 / 256), 256, 0, stream>>>(f_w, g_w, h_w, out_w, w16);
  tcvt_kernel<<<dim3(HW / 64, NC / 64, NB), 256, 0, stream>>>(content, contentT);
  rstcvt_kernel<<<dim3(64, NC / 64, NB), 256, 0, stream>>>(style, styrT);
  convpm2_kernel<<<dim3(HW / 256, 1, 2 * NB), 256, 0, stream>>>(contentT, styrT, fw16, f_b, g_b, fT, gT);
  convcm_kernel<unsigned short><<<dim3(NC / 64, HW / 256, NB), 256, 0, stream>>>(styrT, hw16, h_b, hC, NC);
  attn_kernel<<<dim3(512), 256, 0, stream>>>(fT, gT, hC, midT);
  convcm_kernel<float><<<dim3(NC / 64, HW / 256, NB), 256, 0, stream>>>(midT, ow16, out_b, out, NC);
}